// Round 6
// baseline (119.490 us; speedup 1.0000x reference)
//
#include <hip/hip_runtime.h>
#include <stdint.h>

#define BLOCK 256
#define NW 10             // float4 per thread: NW*BLOCK >= 2401 words
#define CAP 256           // candidate buffer
#define WL0 32            // int offset of word lists in ws
#define WLE 1024          // int2 entries per shift list
#define WS_ROUT 8704      // int offset of per-row partials (float)
static constexpr int LBL = 8;

#define A1 0.1f
#define A2 5.0f
#define A3 10.0f

__device__ __forceinline__ unsigned f2key(float f) {
  unsigned u = __float_as_uint(f);
  return (u & 0x80000000u) ? ~u : (u | 0x80000000u);
}
__device__ __forceinline__ float key2f(unsigned k) {
  unsigned u = (k & 0x80000000u) ? (k & 0x7FFFFFFFu) : ~k;
  return __uint_as_float(u);
}
__device__ __forceinline__ float sigm(float v) { return 1.0f / (1.0f + __expf(-v)); }

// ws[1]=isByteLayout. A 0x01 byte at index %4 != 0 only occurs for 1-byte bools.
__global__ void detect_kernel(const unsigned char* __restrict__ wl, int total,
                              int* __restrict__ ws) {
  int i = blockIdx.x * 256 + threadIdx.x;
  if (i < total && (i & 3) != 0 && wl[i] == 1) atomicOr(&ws[1], 1);
}

// Per shift s: list of {word w, labels packed 4x8b} for full words with any
// whitelisted column. Word w covers cols s+4w .. s+4w+3 (all < C).
// Head cols [0,s) and tail cols [s+4nv, C) get label slots ws[4..7]/ws[8..15].
__global__ void build_kernel(const unsigned char* __restrict__ wl, int C,
                             int* __restrict__ ws) {
  int t = blockIdx.x * 256 + threadIdx.x;
  int isByte = ws[1];
  const int* wlw = (const int*)wl;
  if (t < 12) {  // head/tail label slots
    int c = (t < 4) ? t : C - 8 + (t - 4);
    int lab = 255;
    for (int l = 0; l < LBL; ++l) {
      bool v = isByte ? (wl[(long long)l * C + c] != 0)
                      : (wlw[(long long)l * C + c] != 0);
      if (v) lab = l;
    }
    if (t < 4) ws[4 + t] = lab; else ws[8 + (t - 4)] = lab;
  }
  int s = t / 2404, w = t % 2404;
  if (s < 4) {
    int nv = (C - s) >> 2;
    if (w < nv) {
      unsigned labs = 0xFFFFFFFFu;
      bool any = false;
#pragma unroll
      for (int e = 0; e < 4; ++e) {
        int c = s + 4 * w + e;
        unsigned lab = 255u;
        for (int l = 0; l < LBL; ++l) {
          bool v = isByte ? (wl[(long long)l * C + c] != 0)
                          : (wlw[(long long)l * C + c] != 0);
          if (v) lab = (unsigned)l;
        }
        if (lab < (unsigned)LBL) {
          labs = (labs & ~(255u << (8 * e))) | (lab << (8 * e));
          any = true;
        }
      }
      if (any) {
        int p = atomicAdd(&ws[16 + s], 1);
        if (p < WLE) ((int2*)(ws + WL0))[(size_t)s * WLE + p] = make_int2(w, (int)labs);
      }
    }
  }
}

__global__ __launch_bounds__(BLOCK, 8) void rank_kernel(
    const float* __restrict__ x, const float* __restrict__ y,
    const int* __restrict__ ws, float* __restrict__ rout, int C) {
  __shared__ unsigned hist[2048];  // fallback only
  __shared__ unsigned buf[CAP];
  __shared__ float wtop2[BLOCK / 64];
  __shared__ unsigned wtot[BLOCK / 64];
  __shared__ unsigned lmaxk[LBL];
  __shared__ float smL[LBL];
  __shared__ unsigned gtbits, bufcnt, s_seld, s_selk, s_selc, s_key;

  int tid = threadIdx.x;
  int row = blockIdx.x;
  long long base = (long long)row * C;
  const float* __restrict__ xr = x + base;
  const float* __restrict__ yr = y + base;

  int s = (int)((4 - (base & 3)) & 3);
  int nv = (C - s) >> 2;
  int tail0 = s + 4 * nv;
  int nrem = C - 4 * nv;  // head (s) + tail, <= 5

  const float4* __restrict__ xv4 = (const float4*)(xr + s);
  const float4* __restrict__ yv4 = (const float4*)(yr + s);

  // ---- phase A: issue ALL loads (stream, list entries, gathers, edges) ----
  float4 f[NW];
  bool hv[NW];
#pragma unroll
  for (int t = 0; t < NW; ++t) {
    int i = tid + t * BLOCK;
    hv[t] = (i < nv);
    f[t] = hv[t] ? xv4[i] : make_float4(-INFINITY, -INFINITY, -INFINITY, -INFINITY);
  }
  const int2* __restrict__ wle = (const int2*)(ws + WL0) + (size_t)s * WLE;
  int2 E0 = wle[tid];           // lists padded with -1: no count dependency
  int2 E1 = wle[tid + BLOCK];   // whitelist has <= 400 words total
  float4 yg0 = make_float4(0, 0, 0, 0), xg0 = yg0, yg1 = yg0, xg1 = yg0;
  if (E0.y != -1) { yg0 = yv4[E0.x]; xg0 = xv4[E0.x]; }
  if (E1.y != -1) { yg1 = yv4[E1.x]; xg1 = xv4[E1.x]; }
  float tailv = -INFINITY, tyv = 0.0f;
  bool havet = false;
  int tc = 0, tlab = 255;
  if (tid < nrem) {
    tc = (tid < s) ? tid : tail0 + (tid - s);
    tailv = xr[tc];
    tyv = yr[tc];
    havet = true;
    tlab = (tc < 4) ? ws[4 + tc] : ws[8 + (tc - (C - 8))];
  }
  if (tid < LBL) smL[tid] = xr[tid];  // snapshot x[row,0..7] for epilogue

  // ---- init LDS, barrier BEFORE any LDS atomics ----
  if (tid < LBL) lmaxk[tid] = 0u;
  if (tid == 0) { gtbits = 0u; bufcnt = 0u; }
  __syncthreads();

  // ---- phase B: whitelist atomics from gathered registers ----
  if (E0.y != -1) {
    float fx[4] = {xg0.x, xg0.y, xg0.z, xg0.w};
    float fy[4] = {yg0.x, yg0.y, yg0.z, yg0.w};
    unsigned labs = (unsigned)E0.y;
#pragma unroll
    for (int e = 0; e < 4; ++e) {
      unsigned lab = (labs >> (8 * e)) & 255u;
      if (lab < (unsigned)LBL) {
        atomicMax(&lmaxk[lab], f2key(fx[e]));
        if (fy[e] != 0.0f) atomicOr(&gtbits, 1u << lab);
      }
    }
  }
  if (E1.y != -1) {
    float fx[4] = {xg1.x, xg1.y, xg1.z, xg1.w};
    float fy[4] = {yg1.x, yg1.y, yg1.z, yg1.w};
    unsigned labs = (unsigned)E1.y;
#pragma unroll
    for (int e = 0; e < 4; ++e) {
      unsigned lab = (labs >> (8 * e)) & 255u;
      if (lab < (unsigned)LBL) {
        atomicMax(&lmaxk[lab], f2key(fx[e]));
        if (fy[e] != 0.0f) atomicOr(&gtbits, 1u << lab);
      }
    }
  }
  if (havet && tlab < LBL) {
    atomicMax(&lmaxk[tlab], f2key(tailv));
    if (tyv != 0.0f) atomicOr(&gtbits, 1u << tlab);
  }

  // ---- per-thread max (each thread has >= 9 real words) ----
  float tmax = tailv;
#pragma unroll
  for (int t = 0; t < NW; ++t)
    tmax = fmaxf(tmax, fmaxf(fmaxf(f[t].x, f[t].y), fmaxf(f[t].z, f[t].w)));

  // ---- wave top-2 of thread-maxes; p = min over waves of wave-2nd ----
  float a1 = tmax, a2 = -INFINITY;
#pragma unroll
  for (int st = 1; st < 64; st <<= 1) {
    float b1 = __shfl_xor(a1, st, 64);
    float b2 = __shfl_xor(a2, st, 64);
    float m = fminf(a1, b1);
    float o = (a1 >= b1) ? a2 : b2;
    a1 = fmaxf(a1, b1);
    a2 = fmaxf(m, o);
  }
  int w = tid >> 6;
  if ((tid & 63) == 0) wtop2[w] = a2;
  __syncthreads();
  float p = wtop2[0];
#pragma unroll
  for (int i = 1; i < BLOCK / 64; ++i) p = fminf(p, wtop2[i]);
  // guarantees only >= 2*(BLOCK/64) = 8 candidates; bc<16 -> exact fallback

  // ---- collect candidates >= p ----
#pragma unroll
  for (int t = 0; t < NW; ++t) {
    if (f[t].x >= p) { unsigned q = atomicAdd(&bufcnt, 1u); if (q < CAP) buf[q] = f2key(f[t].x); }
    if (f[t].y >= p) { unsigned q = atomicAdd(&bufcnt, 1u); if (q < CAP) buf[q] = f2key(f[t].y); }
    if (f[t].z >= p) { unsigned q = atomicAdd(&bufcnt, 1u); if (q < CAP) buf[q] = f2key(f[t].z); }
    if (f[t].w >= p) { unsigned q = atomicAdd(&bufcnt, 1u); if (q < CAP) buf[q] = f2key(f[t].w); }
  }
  if (havet && tailv >= p) { unsigned q = atomicAdd(&bufcnt, 1u); if (q < CAP) buf[q] = f2key(tailv); }
  __syncthreads();

  unsigned selkey = 0u;
  int bc = (int)bufcnt;
  if (bc >= 16 && bc <= CAP) {
    // ---- exact rank-16 among candidates; wave 0 only (tie-correct) ----
    if (tid < 64) {
      for (int i = tid; i < bc; i += 64) {
        unsigned mk = buf[i];
        int g = 0, e2 = 0;
        for (int j = 0; j < bc; ++j) {
          unsigned bk = buf[j];  // LDS broadcast
          g += (bk > mk);
          e2 += (bk == mk);
        }
        if (g < 16 && 16 <= g + e2) s_key = mk;  // ties write same value
      }
    }
    __syncthreads();
    selkey = s_key;
  } else {
    // ---- fallback (block-uniform, rare): 3-level histogram select ----
    unsigned prefix = 0, pmask = 0;
    int k = 16;
    bool done = false;
    const int SHa[3] = {21, 10, 0};
    const int WIDa[3] = {11, 11, 10};
    for (int lev = 0; lev < 3 && !done; ++lev) {
      int shift = SHa[lev];
      int nb = 1 << WIDa[lev];
      unsigned bmask = (unsigned)nb - 1u;
      for (int i = tid; i < nb; i += BLOCK) hist[i] = 0;
      if (tid == 0) bufcnt = 0;
      __syncthreads();
#pragma unroll
      for (int t = 0; t < NW; ++t)
        if (hv[t]) {
          unsigned kk[4] = {f2key(f[t].x), f2key(f[t].y), f2key(f[t].z), f2key(f[t].w)};
#pragma unroll
          for (int e = 0; e < 4; ++e)
            if ((kk[e] & pmask) == prefix) atomicAdd(&hist[(kk[e] >> shift) & bmask], 1u);
        }
      if (havet) {
        unsigned tk = f2key(tailv);
        if ((tk & pmask) == prefix) atomicAdd(&hist[(tk >> shift) & bmask], 1u);
      }
      __syncthreads();
      int bpt = nb / BLOCK;
      int b0 = tid * bpt;
      unsigned cs = 0;
      for (int b = 0; b < bpt; ++b) cs += hist[b0 + b];
      unsigned v = cs;
      int lane = tid & 63;
#pragma unroll
      for (int st = 1; st < 64; st <<= 1) {
        unsigned tv = __shfl_down(v, st, 64);
        if (lane + st < 64) v += tv;
      }
      int w2 = tid >> 6;
      if (lane == 0) wtot[w2] = v;
      __syncthreads();
      unsigned above = 0;
      for (int ww = w2 + 1; ww < BLOCK / 64; ++ww) above += wtot[ww];
      unsigned S_incl = v + above;
      unsigned S_excl = S_incl - cs;
      if (S_excl < (unsigned)k && (unsigned)k <= S_incl) {  // unique winner
        int kk2 = k - (int)S_excl;
        int d = b0 + bpt - 1;
        for (; d > b0; --d) {
          int cb = (int)hist[d];
          if (kk2 <= cb) break;
          kk2 -= cb;
        }
        s_seld = (unsigned)d;
        s_selk = (unsigned)kk2;
        s_selc = hist[d];
      }
      __syncthreads();
      prefix |= s_seld << shift;
      pmask |= bmask << shift;
      k = (int)s_selk;
      unsigned selc = s_selc;
      if (lev == 2) {
        selkey = prefix;
        done = true;
      } else if (selc <= (unsigned)CAP) {
#pragma unroll
        for (int t = 0; t < NW; ++t)
          if (hv[t]) {
            unsigned kk[4] = {f2key(f[t].x), f2key(f[t].y), f2key(f[t].z), f2key(f[t].w)};
#pragma unroll
            for (int e = 0; e < 4; ++e)
              if ((kk[e] & pmask) == prefix) {
                unsigned q = atomicAdd(&bufcnt, 1u);
                if (q < CAP) buf[q] = kk[e];
              }
          }
        if (havet) {
          unsigned tk = f2key(tailv);
          if ((tk & pmask) == prefix) {
            unsigned q = atomicAdd(&bufcnt, 1u);
            if (q < CAP) buf[q] = tk;
          }
        }
        __syncthreads();
        int bc2 = (int)bufcnt;
        if (bc2 > CAP) bc2 = CAP;
        unsigned mk = (tid < bc2) ? buf[tid] : 0u;
        int g = 0, e2 = 0;
        for (int j = 0; j < bc2; ++j) {
          unsigned bk = buf[j];
          g += (bk > mk);
          e2 += (bk == mk);
        }
        if (tid < bc2 && g < k && k <= g + e2) s_key = mk;
        __syncthreads();
        selkey = s_key;
        done = true;
      }
    }
  }

  // ---- epilogue: branch select + rank loss ----
  if (tid == 0) {
    float x16 = key2f(selkey);
    float thres = sigm(fmaxf(x16, 0.0f));  // == max(sigmoid(x16), 0.5)
    unsigned gb = gtbits;
    float x1, x2;
    if (gb) {
      int first = __ffs((int)gb) - 1;
      x1 = sigm(key2f(lmaxk[first]));
      float ng = 0.0f;  // max over non-gt labels of sigmoid(x[b, l]), floor 0
      for (int l = 0; l < LBL; ++l)
        if (!((gb >> l) & 1)) ng = fmaxf(ng, sigm(smL[l]));
      x2 = fmaxf(ng, thres);
    } else {
      unsigned um = 0;
      for (int l = 0; l < LBL; ++l) um = um > lmaxk[l] ? um : lmaxk[l];
      x1 = thres;
      x2 = sigm(key2f(um));  // max over whitelist union
    }
    float dd = x2 - x1 + A1;
    float sg = 1.0f / (1.0f + __expf(-A3 * dd));
    rout[row] = (dd > 0.0f) ? A2 * sg : sg;
  }
}

__global__ __launch_bounds__(256) void reduce_kernel(const float* __restrict__ rin,
                                                     float* __restrict__ out, int B) {
  __shared__ float smr[256];
  float acc = 0.0f;
  for (int i = threadIdx.x; i < B; i += 256) acc += rin[i];
  smr[threadIdx.x] = acc;
  __syncthreads();
  for (int st = 128; st > 0; st >>= 1) {
    if (threadIdx.x < st) smr[threadIdx.x] += smr[threadIdx.x + st];
    __syncthreads();
  }
  if (threadIdx.x == 0) out[0] = smr[0];
}

extern "C" void kernel_launch(void* const* d_in, const int* in_sizes, int n_in,
                              void* d_out, int out_size, void* d_ws, size_t ws_size,
                              hipStream_t stream) {
  const float* x = (const float*)d_in[0];
  const float* y = (const float*)d_in[1];
  // d_in[2] (y_neg) is dead code w.r.t. the output.
  const unsigned char* wl = (const unsigned char*)d_in[3];

  int C = in_sizes[3] / LBL;
  int B = in_sizes[0] / C;
  int total = LBL * C;
  int* ws = (int*)d_ws;

  hipMemsetAsync(ws, 0, 32 * 4, stream);                              // flags+counts
  hipMemsetAsync(ws + WL0, 0xFF, (size_t)4 * WLE * 2 * 4, stream);    // lists -> -1
  int nbs = (total + 255) / 256;
  hipLaunchKernelGGL(detect_kernel, dim3(nbs), dim3(256), 0, stream, wl, total, ws);
  int nbb = (4 * 2404 + 255) / 256;
  hipLaunchKernelGGL(build_kernel, dim3(nbb), dim3(256), 0, stream, wl, C, ws);

  hipLaunchKernelGGL(rank_kernel, dim3(B), dim3(BLOCK), 0, stream, x, y, ws,
                     (float*)(ws + WS_ROUT), C);
  hipLaunchKernelGGL(reduce_kernel, dim3(1), dim3(256), 0, stream,
                     (const float*)(ws + WS_ROUT), (float*)d_out, B);
}

// Round 7
// 72.110 us; speedup vs baseline: 1.6571x; 1.6571x over previous
//
#include <hip/hip_runtime.h>
#include <stdint.h>

#define BLOCK 512
#define NW 5              // float4 per thread: NW*BLOCK*4 >= C
#define CAP 512           // candidate buffer; <= BLOCK
#define LISTCAP 1024      // padded whitelist entries (L*S=400 fits)
#define WS_LIST 8         // int offset of padded list in ws
#define WS_ROUT 4096      // int offset of per-row partials (float)
static constexpr int LBL = 8;

#define A1 0.1f
#define A2 5.0f
#define A3 10.0f

__device__ __forceinline__ unsigned f2key(float f) {
  unsigned u = __float_as_uint(f);
  return (u & 0x80000000u) ? ~u : (u | 0x80000000u);
}
__device__ __forceinline__ float key2f(unsigned k) {
  unsigned u = (k & 0x80000000u) ? (k & 0x7FFFFFFFu) : ~k;
  return __uint_as_float(u);
}
__device__ __forceinline__ float sigm(float v) { return 1.0f / (1.0f + __expf(-v)); }

// ws[1]=isByteLayout. A 0x01 byte at index %4 != 0 only occurs for 1-byte bools.
__global__ void detect_kernel(const unsigned char* __restrict__ wl, int total,
                              int* __restrict__ ws) {
  int i = blockIdx.x * 256 + threadIdx.x;
  if (i < total && (i & 3) != 0 && wl[i] == 1) atomicOr(&ws[1], 1);
}

// Packed whitelist entries (label<<16)|col into ws[WS_LIST..]; list pre-memset
// to -1 so rank_kernel needs no count (order irrelevant: max/or commutative).
__global__ void build_kernel(const unsigned char* __restrict__ wl, int C, int total,
                             int* __restrict__ ws) {
  int i = blockIdx.x * 256 + threadIdx.x;
  if (i >= total) return;
  bool v = ws[1] ? (wl[i] != 0) : (((const int*)wl)[i] != 0);
  if (v) {
    int p = atomicAdd(&ws[0], 1);
    if (p < LISTCAP) ws[WS_LIST + p] = ((i / C) << 16) | (i % C);
  }
}

__global__ __launch_bounds__(BLOCK, 8) void rank_kernel(
    const float* __restrict__ x, const float* __restrict__ y,
    const int* __restrict__ ws, float* __restrict__ rout, int C) {
  __shared__ unsigned hist[2048];  // fallback only
  __shared__ unsigned buf[CAP];
  __shared__ float wtop2[BLOCK / 64];
  __shared__ unsigned wtot[BLOCK / 64];
  __shared__ unsigned lmaxk[LBL];
  __shared__ float smL[LBL];
  __shared__ unsigned gtbits, bufcnt, s_seld, s_selk, s_selc, s_key;

  int tid = threadIdx.x;
  int row = blockIdx.x;
  long long base = (long long)row * C;
  const float* __restrict__ xr = x + base;
  const float* __restrict__ yr = y + base;

  int s = (int)((4 - (base & 3)) & 3);  // elems to reach 16B alignment
  int nv = (C - s) >> 2;
  int tail0 = s + 4 * nv;
  int nrem = C - 4 * nv;  // head (s) + tail, <= 6

  // ---- phase A: issue ALL loads up front (stream first: BW-critical) ----
  const float4* __restrict__ xv4 = (const float4*)(xr + s);
  float4 f[NW];
  bool hv[NW];
#pragma unroll
  for (int t = 0; t < NW; ++t) {
    int i = tid + t * BLOCK;
    hv[t] = (i < nv);
    f[t] = hv[t] ? xv4[i] : make_float4(-INFINITY, -INFINITY, -INFINITY, -INFINITY);
  }
  float tailv = -INFINITY;
  bool havet = false;
  if (tid < nrem) {
    int c = (tid < s) ? tid : tail0 + (tid - s);
    tailv = xr[c];
    havet = true;
  }
  if (tid < LBL) smL[tid] = xr[tid];  // snapshot x[row,0..7] for epilogue
  // whitelist entries (L2-resident, padded with -1: no count dependency)
  int e0 = ws[WS_LIST + tid];
  int e1 = ws[WS_LIST + BLOCK + tid];
  float xg0 = 0.0f, yg0 = 0.0f, xg1 = 0.0f, yg1 = 0.0f;
  if (e0 != -1) { int c = e0 & 0xFFFF; xg0 = xr[c]; yg0 = yr[c]; }
  if (e1 != -1) { int c = e1 & 0xFFFF; xg1 = xr[c]; yg1 = yr[c]; }

  // ---- init LDS, then barrier BEFORE any LDS atomics (race-safe) ----
  if (tid < LBL) lmaxk[tid] = 0u;
  if (tid == 0) { gtbits = 0u; bufcnt = 0u; }
  __syncthreads();

  // ---- phase B: whitelist atomics from gathered registers ----
  if (e0 != -1) {
    int l = e0 >> 16;
    atomicMax(&lmaxk[l], f2key(xg0));
    if (yg0 != 0.0f) atomicOr(&gtbits, 1u << l);
  }
  if (e1 != -1) {
    int l = e1 >> 16;
    atomicMax(&lmaxk[l], f2key(xg1));
    if (yg1 != 0.0f) atomicOr(&gtbits, 1u << l);
  }

  // ---- per-thread max ----
  float tmax = tailv;
#pragma unroll
  for (int t = 0; t < NW; ++t)
    tmax = fmaxf(tmax, fmaxf(fmaxf(f[t].x, f[t].y), fmaxf(f[t].z, f[t].w)));

  // ---- wave top-2 of thread-maxes; p = min over waves of wave-2nd ----
  float a1 = tmax, a2 = -INFINITY;
#pragma unroll
  for (int st = 1; st < 64; st <<= 1) {
    float b1 = __shfl_xor(a1, st, 64);
    float b2 = __shfl_xor(a2, st, 64);
    float m = fminf(a1, b1);
    float o = (a1 >= b1) ? a2 : b2;
    a1 = fmaxf(a1, b1);
    a2 = fmaxf(m, o);
  }
  int w = tid >> 6;
  if ((tid & 63) == 0) wtop2[w] = a2;
  __syncthreads();
  float p = wtop2[0];
#pragma unroll
  for (int i = 1; i < BLOCK / 64; ++i) p = fminf(p, wtop2[i]);
  // each of 8 waves has >= 2 thread-maxes >= its own a2 >= p  =>  bc >= 16

  // ---- collect candidates >= p ----
#pragma unroll
  for (int t = 0; t < NW; ++t) {
    if (f[t].x >= p) { unsigned q = atomicAdd(&bufcnt, 1u); if (q < CAP) buf[q] = f2key(f[t].x); }
    if (f[t].y >= p) { unsigned q = atomicAdd(&bufcnt, 1u); if (q < CAP) buf[q] = f2key(f[t].y); }
    if (f[t].z >= p) { unsigned q = atomicAdd(&bufcnt, 1u); if (q < CAP) buf[q] = f2key(f[t].z); }
    if (f[t].w >= p) { unsigned q = atomicAdd(&bufcnt, 1u); if (q < CAP) buf[q] = f2key(f[t].w); }
  }
  if (havet && tailv >= p) { unsigned q = atomicAdd(&bufcnt, 1u); if (q < CAP) buf[q] = f2key(tailv); }
  __syncthreads();

  unsigned selkey = 0u;
  int bc = (int)bufcnt;
  if (bc >= 16 && bc <= CAP) {
    // ---- exact rank-16 among candidates; wave 0 only (tie-correct) ----
    if (tid < 64) {
      for (int i = tid; i < bc; i += 64) {
        unsigned mk = buf[i];
        int g = 0, e2 = 0;
        for (int j = 0; j < bc; ++j) {
          unsigned bk = buf[j];  // LDS broadcast
          g += (bk > mk);
          e2 += (bk == mk);
        }
        if (g < 16 && 16 <= g + e2) s_key = mk;  // ties write same value
      }
    }
    __syncthreads();
    selkey = s_key;
  } else {
    // ---- fallback (block-uniform, pathological data only) ----
    unsigned prefix = 0, pmask = 0;
    int k = 16;
    bool done = false;
    const int SHa[3] = {21, 10, 0};
    const int WIDa[3] = {11, 11, 10};
    for (int lev = 0; lev < 3 && !done; ++lev) {
      int shift = SHa[lev];
      int nb = 1 << WIDa[lev];
      unsigned bmask = (unsigned)nb - 1u;
      for (int i = tid; i < nb; i += BLOCK) hist[i] = 0;
      if (tid == 0) bufcnt = 0;
      __syncthreads();
#pragma unroll
      for (int t = 0; t < NW; ++t)
        if (hv[t]) {
          unsigned kk[4] = {f2key(f[t].x), f2key(f[t].y), f2key(f[t].z), f2key(f[t].w)};
#pragma unroll
          for (int e = 0; e < 4; ++e)
            if ((kk[e] & pmask) == prefix) atomicAdd(&hist[(kk[e] >> shift) & bmask], 1u);
        }
      if (havet) {
        unsigned tk = f2key(tailv);
        if ((tk & pmask) == prefix) atomicAdd(&hist[(tk >> shift) & bmask], 1u);
      }
      __syncthreads();
      int bpt = nb / BLOCK;
      int b0 = tid * bpt;
      unsigned cs = 0;
      for (int b = 0; b < bpt; ++b) cs += hist[b0 + b];
      unsigned v = cs;
      int lane = tid & 63;
#pragma unroll
      for (int st = 1; st < 64; st <<= 1) {
        unsigned tv = __shfl_down(v, st, 64);
        if (lane + st < 64) v += tv;
      }
      int w2 = tid >> 6;
      if (lane == 0) wtot[w2] = v;
      __syncthreads();
      unsigned above = 0;
      for (int ww = w2 + 1; ww < BLOCK / 64; ++ww) above += wtot[ww];
      unsigned S_incl = v + above;
      unsigned S_excl = S_incl - cs;
      if (S_excl < (unsigned)k && (unsigned)k <= S_incl) {  // unique winner
        int kk2 = k - (int)S_excl;
        int d = b0 + bpt - 1;
        for (; d > b0; --d) {
          int cb = (int)hist[d];
          if (kk2 <= cb) break;
          kk2 -= cb;
        }
        s_seld = (unsigned)d;
        s_selk = (unsigned)kk2;
        s_selc = hist[d];
      }
      __syncthreads();
      prefix |= s_seld << shift;
      pmask |= bmask << shift;
      k = (int)s_selk;
      unsigned selc = s_selc;
      if (lev == 2) {
        selkey = prefix;
        done = true;
      } else if (selc <= (unsigned)CAP) {
#pragma unroll
        for (int t = 0; t < NW; ++t)
          if (hv[t]) {
            unsigned kk[4] = {f2key(f[t].x), f2key(f[t].y), f2key(f[t].z), f2key(f[t].w)};
#pragma unroll
            for (int e = 0; e < 4; ++e)
              if ((kk[e] & pmask) == prefix) {
                unsigned q = atomicAdd(&bufcnt, 1u);
                if (q < CAP) buf[q] = kk[e];
              }
          }
        if (havet) {
          unsigned tk = f2key(tailv);
          if ((tk & pmask) == prefix) {
            unsigned q = atomicAdd(&bufcnt, 1u);
            if (q < CAP) buf[q] = tk;
          }
        }
        __syncthreads();
        int bc2 = (int)bufcnt;
        if (bc2 > CAP) bc2 = CAP;
        unsigned mk = (tid < bc2) ? buf[tid] : 0u;
        int g = 0, e2 = 0;
        for (int j = 0; j < bc2; ++j) {
          unsigned bk = buf[j];
          g += (bk > mk);
          e2 += (bk == mk);
        }
        if (tid < bc2 && g < k && k <= g + e2) s_key = mk;
        __syncthreads();
        selkey = s_key;
        done = true;
      }
    }
  }

  // ---- epilogue: branch select + rank loss ----
  if (tid == 0) {
    float x16 = key2f(selkey);
    float thres = sigm(fmaxf(x16, 0.0f));  // == max(sigmoid(x16), 0.5)
    unsigned gb = gtbits;
    float x1, x2;
    if (gb) {
      int first = __ffs((int)gb) - 1;
      x1 = sigm(key2f(lmaxk[first]));
      float ng = 0.0f;  // max over non-gt labels of sigmoid(x[b, l]), floor 0
      for (int l = 0; l < LBL; ++l)
        if (!((gb >> l) & 1)) ng = fmaxf(ng, sigm(smL[l]));
      x2 = fmaxf(ng, thres);
    } else {
      unsigned um = 0;
      for (int l = 0; l < LBL; ++l) um = um > lmaxk[l] ? um : lmaxk[l];
      x1 = thres;
      x2 = sigm(key2f(um));  // max over whitelist union
    }
    float dd = x2 - x1 + A1;
    float sg = 1.0f / (1.0f + __expf(-A3 * dd));
    rout[row] = (dd > 0.0f) ? A2 * sg : sg;
  }
}

__global__ __launch_bounds__(256) void reduce_kernel(const float* __restrict__ rin,
                                                     float* __restrict__ out, int B) {
  __shared__ float smr[256];
  float acc = 0.0f;
  for (int i = threadIdx.x; i < B; i += 256) acc += rin[i];
  smr[threadIdx.x] = acc;
  __syncthreads();
  for (int st = 128; st > 0; st >>= 1) {
    if (threadIdx.x < st) smr[threadIdx.x] += smr[threadIdx.x + st];
    __syncthreads();
  }
  if (threadIdx.x == 0) out[0] = smr[0];
}

extern "C" void kernel_launch(void* const* d_in, const int* in_sizes, int n_in,
                              void* d_out, int out_size, void* d_ws, size_t ws_size,
                              hipStream_t stream) {
  const float* x = (const float*)d_in[0];
  const float* y = (const float*)d_in[1];
  // d_in[2] (y_neg) is dead code w.r.t. the output.
  const unsigned char* wl = (const unsigned char*)d_in[3];

  int C = in_sizes[3] / LBL;
  int B = in_sizes[0] / C;
  int total = LBL * C;
  int* ws = (int*)d_ws;

  hipMemsetAsync(ws, 0, WS_LIST * 4, stream);                       // flags/count
  hipMemsetAsync(ws + WS_LIST, 0xFF, (size_t)LISTCAP * 4, stream);  // list -> -1
  int nbs = (total + 255) / 256;
  hipLaunchKernelGGL(detect_kernel, dim3(nbs), dim3(256), 0, stream, wl, total, ws);
  hipLaunchKernelGGL(build_kernel, dim3(nbs), dim3(256), 0, stream, wl, C, total, ws);

  hipLaunchKernelGGL(rank_kernel, dim3(B), dim3(BLOCK), 0, stream, x, y, ws,
                     (float*)(ws + WS_ROUT), C);
  hipLaunchKernelGGL(reduce_kernel, dim3(1), dim3(256), 0, stream,
                     (const float*)(ws + WS_ROUT), (float*)d_out, B);
}